// Round 1
// baseline (136.773 us; speedup 1.0000x reference)
//
#include <hip/hip_runtime.h>

// TripletLoss: B=384 embeddings of dim 1024 (fp32), labels int32 (16 classes).
// reference: mean over all valid (a,p,n) of relu(D[a,p]-D[a,n]+margin), plus count.
// Algebra: D[a,p]-D[a,n] = H[a,p]-H[a,n] with H[i][j] = sq[j] - 2*dot(e_i,e_j)
// (the sq[a] term cancels), so we never form D itself.

constexpr int BN   = 384;    // batch
constexpr int DIM  = 1024;   // embedding dim
constexpr float MARGIN = 1.0f;

// ---------------------------------------------------------------- sq + init
// 96 blocks x 256 threads; each wave (4/block) computes sq of one row via
// float4 loads + 64-lane shuffle reduce. Block 0 thread 0 zeroes accumulators.
__global__ void sq_init_kernel(const float* __restrict__ E,
                               float* __restrict__ sq,
                               float* __restrict__ total,
                               int* __restrict__ cnt) {
    const int wave = threadIdx.x >> 6;
    const int lane = threadIdx.x & 63;
    const int row  = blockIdx.x * 4 + wave;
    const float4* e4 = reinterpret_cast<const float4*>(E + (size_t)row * DIM);
    float s = 0.f;
#pragma unroll
    for (int i = 0; i < DIM / 256; ++i) {          // 4 iters
        float4 v = e4[i * 64 + lane];
        s += v.x * v.x + v.y * v.y + v.z * v.z + v.w * v.w;
    }
#pragma unroll
    for (int off = 32; off; off >>= 1) s += __shfl_down(s, off);
    if (lane == 0) sq[row] = s;
    if (blockIdx.x == 0 && threadIdx.x == 0) { *total = 0.f; *cnt = 0; }
}

// ---------------------------------------------------------------- H matrix
// Tiled fp32 "gram" with epilogue H[i][j] = sq[j] - 2*dot(i,j).
// grid (12,12), block 16x16; 32x32 tile, 2x2 register block per thread.
__global__ void gram_kernel(const float* __restrict__ E,
                            const float* __restrict__ sq,
                            float* __restrict__ H) {
    __shared__ float As[32][33];
    __shared__ float Bs[32][33];
    const int tx = threadIdx.x, ty = threadIdx.y;
    const int t  = ty * 16 + tx;
    const int i0 = blockIdx.y * 32, j0 = blockIdx.x * 32;
    const int lrow = t >> 3;            // 0..31
    const int lc4  = (t & 7) * 4;       // 0,4,..,28

    float acc00 = 0.f, acc01 = 0.f, acc10 = 0.f, acc11 = 0.f;

    for (int k0 = 0; k0 < DIM; k0 += 32) {
        float4 av = *reinterpret_cast<const float4*>(E + (size_t)(i0 + lrow) * DIM + k0 + lc4);
        float4 bv = *reinterpret_cast<const float4*>(E + (size_t)(j0 + lrow) * DIM + k0 + lc4);
        As[lrow][lc4 + 0] = av.x; As[lrow][lc4 + 1] = av.y;
        As[lrow][lc4 + 2] = av.z; As[lrow][lc4 + 3] = av.w;
        Bs[lrow][lc4 + 0] = bv.x; Bs[lrow][lc4 + 1] = bv.y;
        Bs[lrow][lc4 + 2] = bv.z; Bs[lrow][lc4 + 3] = bv.w;
        __syncthreads();
#pragma unroll
        for (int kk = 0; kk < 32; ++kk) {
            const float a0 = As[2 * ty][kk],     a1 = As[2 * ty + 1][kk];
            const float b0 = Bs[2 * tx][kk],     b1 = Bs[2 * tx + 1][kk];
            acc00 += a0 * b0; acc01 += a0 * b1;
            acc10 += a1 * b0; acc11 += a1 * b1;
        }
        __syncthreads();
    }

    const int r0 = i0 + 2 * ty;
    const int c0 = j0 + 2 * tx;
    const float sc0 = sq[c0], sc1 = sq[c0 + 1];
    H[(size_t)r0 * BN + c0]           = sc0 - 2.f * acc00;
    H[(size_t)r0 * BN + c0 + 1]       = sc1 - 2.f * acc01;
    H[(size_t)(r0 + 1) * BN + c0]     = sc0 - 2.f * acc10;
    H[(size_t)(r0 + 1) * BN + c0 + 1] = sc1 - 2.f * acc11;
}

// ---------------------------------------------------------------- triplet sum
// One block (256 threads) per anchor a. H row + labels in LDS.
// p-loop is wave-uniform (labels in LDS), n-loop thread-parallel.
__global__ void triplet_kernel(const float* __restrict__ H,
                               const int* __restrict__ labels,
                               float* __restrict__ total,
                               int* __restrict__ cnt) {
    __shared__ float Hrow[BN];
    __shared__ int   lab[BN];
    __shared__ float wsum[4];
    __shared__ int   wcnt[4];
    const int a   = blockIdx.x;
    const int tid = threadIdx.x;

    for (int i = tid; i < BN; i += 256) {
        Hrow[i] = H[(size_t)a * BN + i];
        lab[i]  = labels[i];
    }
    __syncthreads();
    const int la = lab[a];

    // nneg (thread-partial, reduced later)
    int lc = 0;
    for (int n = tid; n < BN; n += 256) lc += (lab[n] != la) ? 1 : 0;

    float ls = 0.f;
    int npos = 0;   // uniform across threads
    for (int p = a + 1; p < BN; ++p) {
        if (lab[p] == la) {     // wave-uniform branch
            ++npos;
            const float dap = Hrow[p];
            for (int n = tid; n < BN; n += 256) {
                if (lab[n] != la) {
                    const float v = dap - Hrow[n] + MARGIN;
                    ls += (v > 0.f) ? v : 0.f;
                }
            }
        }
    }

#pragma unroll
    for (int off = 32; off; off >>= 1) {
        ls += __shfl_down(ls, off);
        lc += __shfl_down(lc, off);
    }
    const int wave = tid >> 6, lane = tid & 63;
    if (lane == 0) { wsum[wave] = ls; wcnt[wave] = lc; }
    __syncthreads();
    if (tid == 0) {
        const float s = wsum[0] + wsum[1] + wsum[2] + wsum[3];
        const int nneg = wcnt[0] + wcnt[1] + wcnt[2] + wcnt[3];
        if (s != 0.f) atomicAdd(total, s);
        if (npos)     atomicAdd(cnt, npos * nneg);
    }
}

// ---------------------------------------------------------------- finalize
__global__ void finalize_kernel(const float* __restrict__ total,
                                const int* __restrict__ cnt,
                                float* __restrict__ out) {
    if (threadIdx.x == 0) {
        const int c = *cnt;
        out[0] = (c > 0) ? (*total) / (float)c : 0.f;
        out[1] = (float)c;
    }
}

extern "C" void kernel_launch(void* const* d_in, const int* in_sizes, int n_in,
                              void* d_out, int out_size, void* d_ws, size_t ws_size,
                              hipStream_t stream) {
    const float* E      = (const float*)d_in[0];
    const int*   labels = (const int*)d_in[1];
    float*       out    = (float*)d_out;

    char* ws = (char*)d_ws;
    float* H     = (float*)ws;                                            // 384*384*4 = 589824 B
    float* sq    = (float*)(ws + (size_t)BN * BN * sizeof(float));        // 1536 B
    float* total = (float*)(ws + (size_t)BN * BN * sizeof(float) + BN * sizeof(float));
    int*   cnt   = (int*)  (ws + (size_t)BN * BN * sizeof(float) + BN * sizeof(float) + sizeof(float));

    sq_init_kernel<<<BN / 4, 256, 0, stream>>>(E, sq, total, cnt);
    gram_kernel<<<dim3(BN / 32, BN / 32), dim3(16, 16), 0, stream>>>(E, sq, H);
    triplet_kernel<<<BN, 256, 0, stream>>>(H, labels, total, cnt);
    finalize_kernel<<<1, 64, 0, stream>>>(total, cnt, out);
}

// Round 2
// 83.941 us; speedup vs baseline: 1.6294x; 1.6294x over previous
//
#include <hip/hip_runtime.h>

// TripletLoss: B=384, D=1024 fp32, 16 classes, margin=1.
// H[i][j] = sq[j] - 2*dot(e_i,e_j); loss = relu(H[a,p]-H[a,n]+margin) (sq[a] cancels).
// R1 design: split-K gram (Z partial buffers, Z*144 blocks) -> triplet per-anchor
// blocks that sum partials, build positive list in parallel, reduce -> finalize.

constexpr int BN  = 384;
constexpr int DIM = 1024;
constexpr float MARGIN = 1.0f;

// ---------------------------------------------------------------- gram (split-K)
// grid (12,12,Z), block 16x16. 32x32 tile, 2x2 reg block, K-chunk = DIM/Z.
// LDS tiles stored K-major (Ast[kk][row], pad 34) so fragment reads are float2.
// Prefetches next global chunk between barriers. Diagonal blocks emit sqpart.
__global__ __launch_bounds__(256) void gram_kernel(
    const float* __restrict__ E, float* __restrict__ P,
    float* __restrict__ sqpart, float* __restrict__ total,
    int* __restrict__ cnt, int KC) {
    __shared__ float Ast[32 * 34];
    __shared__ float Bst[32 * 34];
    const int tx = threadIdx.x, ty = threadIdx.y;
    const int t  = ty * 16 + tx;
    const int i0 = blockIdx.y * 32, j0 = blockIdx.x * 32;
    const int z  = blockIdx.z;
    const int lrow = t >> 3;          // 0..31
    const int lc4  = (t & 7) * 4;     // 0,4,..,28

    if (z == 0 && blockIdx.x == 0 && blockIdx.y == 0 && t == 0) {
        *total = 0.f; *cnt = 0;
    }

    const float* Arow = E + (size_t)(i0 + lrow) * DIM + z * KC + lc4;
    const float* Brow = E + (size_t)(j0 + lrow) * DIM + z * KC + lc4;

    float4 av = *reinterpret_cast<const float4*>(Arow);
    float4 bv = *reinterpret_cast<const float4*>(Brow);

    float acc00 = 0.f, acc01 = 0.f, acc10 = 0.f, acc11 = 0.f;

    for (int kt = 0; kt < KC; kt += 32) {
        Ast[(lc4 + 0) * 34 + lrow] = av.x; Ast[(lc4 + 1) * 34 + lrow] = av.y;
        Ast[(lc4 + 2) * 34 + lrow] = av.z; Ast[(lc4 + 3) * 34 + lrow] = av.w;
        Bst[(lc4 + 0) * 34 + lrow] = bv.x; Bst[(lc4 + 1) * 34 + lrow] = bv.y;
        Bst[(lc4 + 2) * 34 + lrow] = bv.z; Bst[(lc4 + 3) * 34 + lrow] = bv.w;
        __syncthreads();
        if (kt + 32 < KC) {                       // prefetch next chunk
            av = *reinterpret_cast<const float4*>(Arow + kt + 32);
            bv = *reinterpret_cast<const float4*>(Brow + kt + 32);
        }
#pragma unroll
        for (int kk = 0; kk < 32; ++kk) {
            const float2 a01 = *reinterpret_cast<const float2*>(&Ast[kk * 34 + 2 * ty]);
            const float2 b01 = *reinterpret_cast<const float2*>(&Bst[kk * 34 + 2 * tx]);
            acc00 += a01.x * b01.x; acc01 += a01.x * b01.y;
            acc10 += a01.y * b01.x; acc11 += a01.y * b01.y;
        }
        __syncthreads();
    }

    const int r0 = i0 + 2 * ty;
    const int c0 = j0 + 2 * tx;
    float* Pz = P + (size_t)z * BN * BN;
    Pz[(size_t)r0 * BN + c0]           = acc00;
    Pz[(size_t)r0 * BN + c0 + 1]       = acc01;
    Pz[(size_t)(r0 + 1) * BN + c0]     = acc10;
    Pz[(size_t)(r0 + 1) * BN + c0 + 1] = acc11;
    if (blockIdx.x == blockIdx.y && tx == ty) {   // diagonal -> sq partials
        sqpart[z * BN + r0]     = acc00;
        sqpart[z * BN + r0 + 1] = acc11;
    }
}

// ---------------------------------------------------------------- triplet sum
// One block per anchor. Sums split-K partials into Hrow, builds the positive
// list in parallel (LDS atomics), then loops over ~npos entries with per-thread
// negatives in registers. No serial 384-iteration scan.
__global__ __launch_bounds__(256) void triplet_kernel(
    const float* __restrict__ P, const float* __restrict__ sqpart,
    const int* __restrict__ labels, float* __restrict__ total,
    int* __restrict__ cnt, int NZ) {
    __shared__ float Hrow[BN];
    __shared__ int   lab[BN];
    __shared__ int   poslist[BN];
    __shared__ int   npos_s;
    __shared__ float wsum[4];
    __shared__ int   wcnt[4];
    const int a   = blockIdx.x;
    const int tid = threadIdx.x;

    if (tid == 0) npos_s = 0;
    for (int i = tid; i < BN; i += 256) {
        float g = 0.f, s = 0.f;
        for (int zz = 0; zz < NZ; ++zz) {
            g += P[(size_t)zz * BN * BN + (size_t)a * BN + i];
            s += sqpart[zz * BN + i];
        }
        Hrow[i] = s - 2.f * g;
        lab[i]  = labels[i];
    }
    __syncthreads();
    const int la = lab[a];

    int lc = 0;                       // per-thread negative count
    for (int p = tid; p < BN; p += 256) {
        if (lab[p] != la) ++lc;
        else if (p > a) { int k = atomicAdd(&npos_s, 1); poslist[k] = p; }
    }
    __syncthreads();
    const int np = npos_s;

    // per-thread negatives cached in registers (BN=384, block=256 -> <=2 each)
    const float hn0  = Hrow[tid];
    const bool  neg0 = (lab[tid] != la);
    const bool  has1 = (tid + 256 < BN);
    const float hn1  = has1 ? Hrow[tid + 256] : 0.f;
    const bool  neg1 = has1 && (lab[tid + 256] != la);

    float ls = 0.f;
    for (int k = 0; k < np; ++k) {
        const float dpm = Hrow[poslist[k]] + MARGIN;
        if (neg0) { const float v = dpm - hn0; ls += (v > 0.f) ? v : 0.f; }
        if (neg1) { const float v = dpm - hn1; ls += (v > 0.f) ? v : 0.f; }
    }

#pragma unroll
    for (int off = 32; off; off >>= 1) {
        ls += __shfl_down(ls, off);
        lc += __shfl_down(lc, off);
    }
    const int wave = tid >> 6, lane = tid & 63;
    if (lane == 0) { wsum[wave] = ls; wcnt[wave] = lc; }
    __syncthreads();
    if (tid == 0) {
        const float s    = wsum[0] + wsum[1] + wsum[2] + wsum[3];
        const int   nneg = wcnt[0] + wcnt[1] + wcnt[2] + wcnt[3];
        if (s != 0.f) atomicAdd(total, s);
        if (np)       atomicAdd(cnt, np * nneg);
    }
}

// ---------------------------------------------------------------- finalize
__global__ void finalize_kernel(const float* __restrict__ total,
                                const int* __restrict__ cnt,
                                float* __restrict__ out) {
    if (threadIdx.x == 0) {
        const int c = *cnt;
        out[0] = (c > 0) ? (*total) / (float)c : 0.f;
        out[1] = (float)c;
    }
}

extern "C" void kernel_launch(void* const* d_in, const int* in_sizes, int n_in,
                              void* d_out, int out_size, void* d_ws, size_t ws_size,
                              hipStream_t stream) {
    const float* E      = (const float*)d_in[0];
    const int*   labels = (const int*)d_in[1];
    float*       out    = (float*)d_out;

    // pick split-K factor that fits the workspace
    int Z = 1;
    for (int cand : {8, 4, 2}) {
        size_t need = (size_t)cand * BN * BN * 4 + (size_t)cand * BN * 4 + 64;
        if (need <= ws_size) { Z = cand; break; }
    }

    char*  ws     = (char*)d_ws;
    float* P      = (float*)ws;
    float* sqpart = (float*)(ws + (size_t)Z * BN * BN * 4);
    float* total  = (float*)(ws + (size_t)Z * BN * BN * 4 + (size_t)Z * BN * 4);
    int*   cnt    = (int*)(total + 1);

    gram_kernel<<<dim3(BN / 32, BN / 32, Z), dim3(16, 16), 0, stream>>>(
        E, P, sqpart, total, cnt, DIM / Z);
    triplet_kernel<<<BN, 256, 0, stream>>>(P, sqpart, labels, total, cnt, Z);
    finalize_kernel<<<1, 64, 0, stream>>>(total, cnt, out);
}

// Round 3
// 82.327 us; speedup vs baseline: 1.6613x; 1.0196x over previous
//
#include <hip/hip_runtime.h>

// TripletLoss: B=384, D=1024 fp32, 16 classes, margin=1.
// H[i][j] = sq[j] - 2*dot(e_i,e_j); loss = relu(H[a,p]-H[a,n]+margin) (sq[a] cancels).
// R3: 2 dispatches. gram: 64x64 tile, 4x4 reg block, split-K Z=16 (576 blocks),
// K-major LDS tiles w/ XOR-16 swizzle (conflict-free writes AND b128 reads).
// triplet: per-anchor 128-thread blocks, contiguous partial layout P[r][z][c],
// templated-NZ unrolled reduction, last-block ticket finalize (no 3rd kernel).

constexpr int BN  = 384;
constexpr int DIM = 1024;
constexpr float MARGIN = 1.0f;
constexpr int LDK = 68;   // K-major LDS row stride (floats); 68*4B is 16B-aligned

// ---------------------------------------------------------------- gram (split-K)
// grid (6,6,Z), block 16x16. Thread t stages row r=t>>2, k-quarter kq=t&3
// (coalesced: 4 lanes cover 128B of one row across the a0/a1 pair).
// LDS element (k,row) lives at [k*LDK + (row ^ ((k>>3)<<4))] -> bank-clean.
__global__ __launch_bounds__(256) void gram_kernel(
    const float* __restrict__ E, float* __restrict__ P,
    float* __restrict__ sqpart, float* __restrict__ total,
    int* __restrict__ cnt, int* __restrict__ ticket, int KC, int NZ) {
    __shared__ float Ast[32 * LDK];
    __shared__ float Bst[32 * LDK];
    const int tx = threadIdx.x, ty = threadIdx.y;
    const int t  = ty * 16 + tx;
    const int i0 = blockIdx.y * 64, j0 = blockIdx.x * 64;
    const int z  = blockIdx.z;

    if (z == 0 && blockIdx.x == 0 && blockIdx.y == 0 && t == 0) {
        *total = 0.f; *cnt = 0; *ticket = 0;
    }

    const int r  = t >> 2;              // 0..63 staged row
    const int kq = t & 3;               // 0..3  k-quarter (8 k's)
    const int kb = kq * 8;
    const int rs = r ^ (kq << 4);       // swizzled LDS row

    const float* Ab = E + (size_t)(i0 + r) * DIM + z * KC + kb;
    const float* Bb = E + (size_t)(j0 + r) * DIM + z * KC + kb;

    float4 a0 = *(const float4*)(Ab);
    float4 a1 = *(const float4*)(Ab + 4);
    float4 b0 = *(const float4*)(Bb);
    float4 b1 = *(const float4*)(Bb + 4);

    float acc[4][4] = {};

    for (int kt = 0; kt < KC; kt += 32) {
        Ast[(kb + 0) * LDK + rs] = a0.x; Ast[(kb + 1) * LDK + rs] = a0.y;
        Ast[(kb + 2) * LDK + rs] = a0.z; Ast[(kb + 3) * LDK + rs] = a0.w;
        Ast[(kb + 4) * LDK + rs] = a1.x; Ast[(kb + 5) * LDK + rs] = a1.y;
        Ast[(kb + 6) * LDK + rs] = a1.z; Ast[(kb + 7) * LDK + rs] = a1.w;
        Bst[(kb + 0) * LDK + rs] = b0.x; Bst[(kb + 1) * LDK + rs] = b0.y;
        Bst[(kb + 2) * LDK + rs] = b0.z; Bst[(kb + 3) * LDK + rs] = b0.w;
        Bst[(kb + 4) * LDK + rs] = b1.x; Bst[(kb + 5) * LDK + rs] = b1.y;
        Bst[(kb + 6) * LDK + rs] = b1.z; Bst[(kb + 7) * LDK + rs] = b1.w;
        __syncthreads();
        if (kt + 32 < KC) {             // prefetch next chunk
            a0 = *(const float4*)(Ab + kt + 32);
            a1 = *(const float4*)(Ab + kt + 36);
            b0 = *(const float4*)(Bb + kt + 32);
            b1 = *(const float4*)(Bb + kt + 36);
        }
#pragma unroll
        for (int kk = 0; kk < 32; ++kk) {
            const int sw = (kk >> 3) << 4;
            const float4 av = *(const float4*)&Ast[kk * LDK + ((4 * ty) ^ sw)];
            const float4 bv = *(const float4*)&Bst[kk * LDK + ((4 * tx) ^ sw)];
            const float aa[4] = {av.x, av.y, av.z, av.w};
            const float bb[4] = {bv.x, bv.y, bv.z, bv.w};
#pragma unroll
            for (int i2 = 0; i2 < 4; ++i2)
#pragma unroll
                for (int j2 = 0; j2 < 4; ++j2)
                    acc[i2][j2] += aa[i2] * bb[j2];
        }
        __syncthreads();
    }

    const size_t rowstride = (size_t)NZ * BN;
#pragma unroll
    for (int i2 = 0; i2 < 4; ++i2) {
        const float4 w = make_float4(acc[i2][0], acc[i2][1], acc[i2][2], acc[i2][3]);
        *(float4*)&P[(size_t)(i0 + 4 * ty + i2) * rowstride + (size_t)z * BN + (j0 + 4 * tx)] = w;
    }
    if (blockIdx.x == blockIdx.y && tx == ty) {       // diagonal -> sq partials
#pragma unroll
        for (int i2 = 0; i2 < 4; ++i2)
            sqpart[z * BN + (i0 + 4 * ty + i2)] = acc[i2][i2];
    }
}

// ---------------------------------------------------------------- triplet + finalize
// One 128-thread block per anchor. Hrow from NZ contiguous float4 partials
// (fully unrolled). Negatives in 3 regs (128*3 = 384). Ticket-based last-block
// finalize writes out[0..1] directly.
template <int NZ>
__global__ __launch_bounds__(128) void triplet_kernel(
    const float* __restrict__ P, const float* __restrict__ sqpart,
    const int* __restrict__ labels, float* __restrict__ total,
    int* __restrict__ cnt, int* __restrict__ ticket, float* __restrict__ out) {
    __shared__ float Hrow[BN];
    __shared__ int   lab[BN];
    __shared__ int   poslist[BN];
    __shared__ int   npos_s;
    __shared__ float wsum[2];
    __shared__ int   wcnt[2];
    const int a   = blockIdx.x;
    const int tid = threadIdx.x;

    if (tid == 0) npos_s = 0;
    for (int i = tid; i < BN; i += 128) lab[i] = labels[i];

    if (tid < 96) {
        const int c0 = tid * 4;
        float4 g = make_float4(0.f, 0.f, 0.f, 0.f);
        float4 s = make_float4(0.f, 0.f, 0.f, 0.f);
#pragma unroll
        for (int z = 0; z < NZ; ++z) {
            const float4 pv = *(const float4*)&P[(size_t)a * ((size_t)NZ * BN) + z * BN + c0];
            const float4 sv = *(const float4*)&sqpart[z * BN + c0];
            g.x += pv.x; g.y += pv.y; g.z += pv.z; g.w += pv.w;
            s.x += sv.x; s.y += sv.y; s.z += sv.z; s.w += sv.w;
        }
        Hrow[c0 + 0] = s.x - 2.f * g.x;
        Hrow[c0 + 1] = s.y - 2.f * g.y;
        Hrow[c0 + 2] = s.z - 2.f * g.z;
        Hrow[c0 + 3] = s.w - 2.f * g.w;
    }
    __syncthreads();

    const int la = lab[a];
    int lc = 0;
#pragma unroll
    for (int q = 0; q < 3; ++q) {
        const int p = tid + q * 128;
        if (lab[p] != la) ++lc;
        else if (p > a) { const int k = atomicAdd(&npos_s, 1); poslist[k] = p; }
    }
    __syncthreads();
    const int np = npos_s;

    const float hn0 = Hrow[tid];
    const float hn1 = Hrow[tid + 128];
    const float hn2 = Hrow[tid + 256];
    const bool  ng0 = (lab[tid]       != la);
    const bool  ng1 = (lab[tid + 128] != la);
    const bool  ng2 = (lab[tid + 256] != la);

    float ls = 0.f;
    for (int k = 0; k < np; ++k) {
        const float dpm = Hrow[poslist[k]] + MARGIN;
        if (ng0) { const float v = dpm - hn0; ls += (v > 0.f) ? v : 0.f; }
        if (ng1) { const float v = dpm - hn1; ls += (v > 0.f) ? v : 0.f; }
        if (ng2) { const float v = dpm - hn2; ls += (v > 0.f) ? v : 0.f; }
    }

#pragma unroll
    for (int off = 32; off; off >>= 1) {
        ls += __shfl_down(ls, off);
        lc += __shfl_down(lc, off);
    }
    const int wave = tid >> 6, lane = tid & 63;
    if (lane == 0) { wsum[wave] = ls; wcnt[wave] = lc; }
    __syncthreads();
    if (tid == 0) {
        const float s    = wsum[0] + wsum[1];
        const int   nneg = wcnt[0] + wcnt[1];
        if (s != 0.f) atomicAdd(total, s);
        if (np)       atomicAdd(cnt, np * nneg);
        __threadfence();
        const int done = atomicAdd(ticket, 1);
        if (done == (int)gridDim.x - 1) {       // last block: finalize
            const float tot = atomicAdd(total, 0.0f);
            const int   c   = atomicAdd(cnt, 0);
            out[0] = (c > 0) ? tot / (float)c : 0.f;
            out[1] = (float)c;
        }
    }
}

extern "C" void kernel_launch(void* const* d_in, const int* in_sizes, int n_in,
                              void* d_out, int out_size, void* d_ws, size_t ws_size,
                              hipStream_t stream) {
    const float* E      = (const float*)d_in[0];
    const int*   labels = (const int*)d_in[1];
    float*       out    = (float*)d_out;

    int Z = 1;
    for (int cand : {16, 8, 4, 2}) {
        size_t need = (size_t)cand * BN * BN * 4 + (size_t)cand * BN * 4 + 64;
        if (need <= ws_size) { Z = cand; break; }
    }

    char*  ws     = (char*)d_ws;
    float* P      = (float*)ws;                                       // BN x (Z*BN)
    float* sqpart = (float*)(ws + (size_t)Z * BN * BN * 4);           // Z x BN
    float* total  = (float*)(ws + (size_t)Z * BN * BN * 4 + (size_t)Z * BN * 4);
    int*   cnt    = (int*)(total + 1);
    int*   ticket = (int*)(total + 2);

    gram_kernel<<<dim3(6, 6, Z), dim3(16, 16), 0, stream>>>(
        E, P, sqpart, total, cnt, ticket, DIM / Z, Z);

    switch (Z) {
        case 16: triplet_kernel<16><<<BN, 128, 0, stream>>>(P, sqpart, labels, total, cnt, ticket, out); break;
        case 8:  triplet_kernel<8> <<<BN, 128, 0, stream>>>(P, sqpart, labels, total, cnt, ticket, out); break;
        case 4:  triplet_kernel<4> <<<BN, 128, 0, stream>>>(P, sqpart, labels, total, cnt, ticket, out); break;
        case 2:  triplet_kernel<2> <<<BN, 128, 0, stream>>>(P, sqpart, labels, total, cnt, ticket, out); break;
        default: triplet_kernel<1> <<<BN, 128, 0, stream>>>(P, sqpart, labels, total, cnt, ticket, out); break;
    }
}